// Round 4
// baseline (66.009 us; speedup 1.0000x reference)
//
#include <hip/hip_runtime.h>
#include <cmath>

// Problem constants
#define SS 2048
#define BB 32
#define HH 1024

// ---------------------------------------------------------------------------
// K1a: partial u[h] over 16-wide k-chunks: partial[c][h] = sum_{k in chunk c}
//      v[k] * We[k][h],  We[k][h] = attn_W[k][HH + h]
// grid (4, 64), block 256 -> 256 blocks, 16KB coalesced read each
// ---------------------------------------------------------------------------
__global__ __launch_bounds__(256) void partial_u_kernel(
    const float* __restrict__ W, const float* __restrict__ v,
    float* __restrict__ partial) {
  int h  = blockIdx.x * 256 + threadIdx.x;  // 0..1023
  int k0 = blockIdx.y * 16;
  float acc = 0.f;
#pragma unroll
  for (int k = k0; k < k0 + 16; ++k)
    acc += v[k] * W[(size_t)k * (2 * HH) + HH + h];
  partial[blockIdx.y * HH + h] = acc;
}

// K1b: u[h] = sum of 64 partials (deterministic, fixed order)
__global__ __launch_bounds__(256) void reduce_u_kernel(
    const float* __restrict__ partial, float* __restrict__ u) {
  int h = blockIdx.x * 256 + threadIdx.x;
  float acc = 0.f;
#pragma unroll
  for (int c = 0; c < 64; ++c) acc += partial[c * HH + h];
  u[h] = acc;
}

// ---------------------------------------------------------------------------
// K2: energy[b*S + s] = dot(enc[s,b,:], u)   -- the 256 MiB streaming kernel
// PROVEN round-1 structure: one wave (64 lanes) per row (row = s*B + b),
// 2048 blocks -> 32 waves/CU of TLP. Plain float4 loads (no nt hint: round-3
// showed nt + fewer waves regressed 53 -> 61 us). u hits L1 (4 KB).
// ---------------------------------------------------------------------------
__global__ __launch_bounds__(256) void energy_kernel(
    const float* __restrict__ enc, const float* __restrict__ u,
    float* __restrict__ energy) {
  int wid  = blockIdx.x * 4 + (threadIdx.x >> 6);  // 0 .. S*B-1  ( = s*B + b )
  int lane = threadIdx.x & 63;
  const float4* e4 = reinterpret_cast<const float4*>(enc) + (size_t)wid * (HH / 4);
  const float4* u4 = reinterpret_cast<const float4*>(u);
  float acc = 0.f;
#pragma unroll
  for (int j = 0; j < 4; ++j) {
    float4 ev = e4[lane + j * 64];
    float4 uv = u4[lane + j * 64];
    acc += ev.x * uv.x + ev.y * uv.y + ev.z * uv.z + ev.w * uv.w;
  }
#pragma unroll
  for (int m = 32; m; m >>= 1) acc += __shfl_xor(acc, m, 64);
  if (lane == 0) {
    int s_ = wid / BB;
    int b_ = wid % BB;
    energy[(size_t)b_ * SS + s_] = acc;
  }
}

// ---------------------------------------------------------------------------
// K3: in-place row softmax on d_out: 32 rows of 2048. One block per row.
// ---------------------------------------------------------------------------
__global__ __launch_bounds__(256) void softmax_kernel(float* __restrict__ e) {
  int b = blockIdx.x;
  float* row = e + (size_t)b * SS;
  int tid  = threadIdx.x;
  int lane = tid & 63;
  int wv   = tid >> 6;

  float vals[8];
  float mx = -INFINITY;
#pragma unroll
  for (int i = 0; i < 8; ++i) {
    vals[i] = row[tid + i * 256];
    mx = fmaxf(mx, vals[i]);
  }
#pragma unroll
  for (int m = 32; m; m >>= 1) mx = fmaxf(mx, __shfl_xor(mx, m, 64));

  __shared__ float red_max[4];
  __shared__ float red_sum[4];
  if (lane == 0) red_max[wv] = mx;
  __syncthreads();
  mx = fmaxf(fmaxf(red_max[0], red_max[1]), fmaxf(red_max[2], red_max[3]));

  float sum = 0.f;
#pragma unroll
  for (int i = 0; i < 8; ++i) {
    vals[i] = expf(vals[i] - mx);
    sum += vals[i];
  }
#pragma unroll
  for (int m = 32; m; m >>= 1) sum += __shfl_xor(sum, m, 64);
  if (lane == 0) red_sum[wv] = sum;
  __syncthreads();
  sum = red_sum[0] + red_sum[1] + red_sum[2] + red_sum[3];

  float inv = 1.0f / sum;
#pragma unroll
  for (int i = 0; i < 8; ++i) row[tid + i * 256] = vals[i] * inv;
}

extern "C" void kernel_launch(void* const* d_in, const int* in_sizes, int n_in,
                              void* d_out, int out_size, void* d_ws, size_t ws_size,
                              hipStream_t stream) {
  const float* enc = (const float*)d_in[0];   // (S,B,H)
  // d_in[1] rnn_hidden, d_in[3] attn_b: cancel under softmax (shift-invariant)
  const float* W = (const float*)d_in[2];     // (H, 2H)
  const float* v = (const float*)d_in[4];     // (1, H)
  float* out = (float*)d_out;                 // (B,1,S) = B*S floats

  float* u       = (float*)d_ws;              // 4 KB
  float* partial = (float*)d_ws + HH;         // 256 KB

  partial_u_kernel<<<dim3(4, 64), 256, 0, stream>>>(W, v, partial);
  reduce_u_kernel<<<4, 256, 0, stream>>>(partial, u);
  energy_kernel<<<(SS * BB) / 4, 256, 0, stream>>>(enc, u, out);
  softmax_kernel<<<BB, 256, 0, stream>>>(out);
}

// Round 5
// 52.946 us; speedup vs baseline: 1.2467x; 1.2467x over previous
//
#include <hip/hip_runtime.h>
#include <cmath>

// Problem constants
#define SS 2048
#define BB 32
#define HH 1024

// ---------------------------------------------------------------------------
// K1a: partial u[h] = sum over a 64-wide k-chunk of v[k] * We[k][h]
//      We[k][h] = attn_W[k][HH + h], attn_W row-major (HH, 2*HH)
// grid (4, 16), block 256  -> 64 blocks, each reads 64KB (latency-hidden)
// ---------------------------------------------------------------------------
__global__ __launch_bounds__(256) void partial_u_kernel(
    const float* __restrict__ W, const float* __restrict__ v,
    float* __restrict__ partial) {
  int h  = blockIdx.x * 256 + threadIdx.x;  // 0..1023
  int k0 = blockIdx.y * 64;
  float acc = 0.f;
#pragma unroll 8
  for (int k = k0; k < k0 + 64; ++k)
    acc += v[k] * W[(size_t)k * (2 * HH) + HH + h];
  partial[blockIdx.y * HH + h] = acc;
}

// K1b: u[h] = sum of 16 partials (deterministic, no atomics)
__global__ __launch_bounds__(256) void reduce_u_kernel(
    const float* __restrict__ partial, float* __restrict__ u) {
  int h = blockIdx.x * 256 + threadIdx.x;
  float acc = 0.f;
#pragma unroll
  for (int c = 0; c < 16; ++c) acc += partial[c * HH + h];
  u[h] = acc;
}

// ---------------------------------------------------------------------------
// K2: energy[b*S + s] = dot(enc[s,b,:], u)   -- the 256 MiB streaming kernel
// one wave (64 lanes) per (s,b); wid = s*B + b so consecutive waves read
// consecutive 4KB rows. Each lane: 4x float4 coalesced, u hits L1.
// ---------------------------------------------------------------------------
__global__ __launch_bounds__(256) void energy_kernel(
    const float* __restrict__ enc, const float* __restrict__ u,
    float* __restrict__ energy) {
  int wid  = blockIdx.x * 4 + (threadIdx.x >> 6);  // 0 .. S*B-1  ( = s*B + b )
  int lane = threadIdx.x & 63;
  const float4* e4 = reinterpret_cast<const float4*>(enc) + (size_t)wid * (HH / 4);
  const float4* u4 = reinterpret_cast<const float4*>(u);
  float acc = 0.f;
#pragma unroll
  for (int j = 0; j < 4; ++j) {
    float4 ev = e4[lane + j * 64];
    float4 uv = u4[lane + j * 64];
    acc += ev.x * uv.x + ev.y * uv.y + ev.z * uv.z + ev.w * uv.w;
  }
#pragma unroll
  for (int m = 32; m; m >>= 1) acc += __shfl_xor(acc, m, 64);
  if (lane == 0) {
    int s_ = wid / BB;
    int b_ = wid % BB;
    energy[(size_t)b_ * SS + s_] = acc;
  }
}

// ---------------------------------------------------------------------------
// K3: in-place row softmax on d_out: 32 rows of 2048. One block per row.
// ---------------------------------------------------------------------------
__global__ __launch_bounds__(256) void softmax_kernel(float* __restrict__ e) {
  int b = blockIdx.x;
  float* row = e + (size_t)b * SS;
  int tid  = threadIdx.x;
  int lane = tid & 63;
  int wv   = tid >> 6;

  float vals[8];
  float mx = -INFINITY;
#pragma unroll
  for (int i = 0; i < 8; ++i) {
    vals[i] = row[tid + i * 256];
    mx = fmaxf(mx, vals[i]);
  }
#pragma unroll
  for (int m = 32; m; m >>= 1) mx = fmaxf(mx, __shfl_xor(mx, m, 64));

  __shared__ float red_max[4];
  __shared__ float red_sum[4];
  if (lane == 0) red_max[wv] = mx;
  __syncthreads();
  mx = fmaxf(fmaxf(red_max[0], red_max[1]), fmaxf(red_max[2], red_max[3]));

  float sum = 0.f;
#pragma unroll
  for (int i = 0; i < 8; ++i) {
    vals[i] = expf(vals[i] - mx);
    sum += vals[i];
  }
#pragma unroll
  for (int m = 32; m; m >>= 1) sum += __shfl_xor(sum, m, 64);
  if (lane == 0) red_sum[wv] = sum;
  __syncthreads();
  sum = red_sum[0] + red_sum[1] + red_sum[2] + red_sum[3];

  float inv = 1.0f / sum;
#pragma unroll
  for (int i = 0; i < 8; ++i) row[tid + i * 256] = vals[i] * inv;
}

extern "C" void kernel_launch(void* const* d_in, const int* in_sizes, int n_in,
                              void* d_out, int out_size, void* d_ws, size_t ws_size,
                              hipStream_t stream) {
  const float* enc = (const float*)d_in[0];   // (S,B,H)
  // d_in[1] rnn_hidden, d_in[3] attn_b: cancel under softmax (shift-invariant)
  const float* W = (const float*)d_in[2];     // (H, 2H)
  const float* v = (const float*)d_in[4];     // (1, H)
  float* out = (float*)d_out;                 // (B,1,S) = B*S floats

  float* u       = (float*)d_ws;              // 4 KB
  float* partial = (float*)d_ws + HH;         // 64 KB

  partial_u_kernel<<<dim3(4, 16), 256, 0, stream>>>(W, v, partial);
  reduce_u_kernel<<<4, 256, 0, stream>>>(partial, u);
  energy_kernel<<<(SS * BB) / 4, 256, 0, stream>>>(enc, u, out);
  softmax_kernel<<<BB, 256, 0, stream>>>(out);
}